// Round 1
// baseline (199.016 us; speedup 1.0000x reference)
//
#include <hip/hip_runtime.h>

#define NCH 30        // NUM_CHARS + 2
#define ML 16         // MAX_LEN
#define NW 1000       // NUM_WORDS
#define NBS 64        // BSZ * SEQ
#define DA_STRIDE 32

// Build global DA table: DA[i][c] = last row i' <= i such that char c appears
// at x[:,:, (i'-2) & 15] for ANY (b,s). Row 0 = all zeros.
__global__ void build_da_kernel(const int* __restrict__ x, int* __restrict__ DA) {
    int c = threadIdx.x;
    if (c >= NCH) return;
    DA[c] = 0;
    int prev = 0;
    for (int i = 1; i <= ML; ++i) {
        int pos = (i - 2) & (ML - 1);        // i=1 -> 15 (negative-index wrap)
        int found = 0;
        for (int n = 0; n < NBS; ++n)
            found |= (x[n * ML + pos] == c) ? 1 : 0;
        int val = found ? i : prev;
        DA[i * DA_STRIDE + c] = val;
        prev = val;
    }
}

__global__ __launch_bounds__(64) void dl_dp_kernel(
    const int* __restrict__ x,
    const int* __restrict__ words,
    const int* __restrict__ word_lengths,
    const float* __restrict__ out_scale,
    const int* __restrict__ DA,
    float* __restrict__ out)
{
    // 16x16 DP cells per lane, [cell][lane] layout: all accesses are
    // lane-stride-1 -> 2 lanes/bank (free). 64 KiB total.
    __shared__ float dmat[ML * ML * 64];
    const int lane = threadIdx.x;
    const int bs = blockIdx.x >> 4;          // 0..63  (b*SEQ + s)
    const int chunk = blockIdx.x & 15;       // 0..15
    const int w_raw = chunk * 64 + lane;
    const bool active = (w_raw < NW);
    const int w = active ? w_raw : (NW - 1); // clamp; inactive lanes skip store
    const float s = out_scale[0];

    float* __restrict__ dl = &dmat[lane];

    // seq_wl = argmin over x row (first index of min) — wave-uniform
    const int* xr = x + bs * ML;
    int minv = xr[0], seq_wl = 0;
    #pragma unroll
    for (int t = 1; t < ML; ++t) {
        int v = xr[t];
        if (v < minv) { minv = v; seq_wl = t; }
    }

    // per-lane word chars + length
    int wc[ML];
    #pragma unroll
    for (int t = 0; t < ML; ++t) wc[t] = words[w * ML + t];
    const int wl = word_lengths[w];

    const float maxdist = ((float)seq_wl + (float)wl) * s;

    for (int i = 1; i <= ML; ++i) {
        const int xi = xr[(i - 2) & (ML - 1)];          // i=1 -> x[...,15]
        const int* dai = DA + i * DA_STRIDE;
        const int* daiprev = dai - DA_STRIDE;

        // ---- j = 1: word char = wc[15]; l = 0 (db init); k from row i-1 of DA
        const int wcj1 = wc[ML - 1];
        const int k1 = daiprev[wcj1];
        const float cost1 = (xi != wcj1) ? 1.0f : 0.0f;
        const float up1 = (i == 1) ? maxdist : dl[((i - 2) * ML) * 64];
        // l==0 -> d[k][0] = maxdist; trans = maxdist + (i-k-1)+1+(1-0-1)
        const float trans1 = maxdist + (float)(i - k1);
        float left_val = fminf(fminf(up1 + 1.0f, maxdist + 1.0f),
                               fminf(maxdist + cost1, trans1));
        dl[((i - 1) * ML) * 64] = left_val;
        bool prev_match = (cost1 == 0.0f);

        // ---- j = 2..16: word char = wc[j-2]; k from row i of DA (da set after j=1)
        #pragma unroll
        for (int j = 2; j <= ML; ++j) {
            const int wcj = wc[j - 2];
            const int k = dai[wcj];
            const float cost = (xi != wcj) ? 1.0f : 0.0f;
            const int l = prev_match ? (j - 1) : 0;      // db from previous column
            float up, diag;
            if (i == 1) { up = maxdist; diag = maxdist; }
            else {
                up   = dl[((i - 2) * ML + (j - 1)) * 64];
                diag = dl[((i - 2) * ML + (j - 2)) * 64];
            }
            float dtrans = maxdist;                      // k==0 or l==0 -> border
            if (l != 0 && k != 0)
                dtrans = dl[((k - 1) * ML + (l - 1)) * 64];
            const float trans = dtrans + (float)(i - k + j - l - 1);
            const float cell = fminf(fminf(up + 1.0f, left_val + 1.0f),
                                     fminf(diag + cost, trans));
            dl[((i - 1) * ML + (j - 1)) * 64] = cell;
            left_val = cell;
            prev_match = (cost == 0.0f);
        }
    }

    // Extraction: d[wl+1][seq_wl+1]. wl==16 -> never-written row 17 -> 0.
    float res = 0.0f;
    if (wl <= ML - 1)
        res = dl[(wl * ML + seq_wl) * 64];
    if (active)
        out[bs * NW + w] = res;
}

extern "C" void kernel_launch(void* const* d_in, const int* in_sizes, int n_in,
                              void* d_out, int out_size, void* d_ws, size_t ws_size,
                              hipStream_t stream) {
    const int*   x            = (const int*)d_in[0];
    const int*   words        = (const int*)d_in[1];
    const int*   word_lengths = (const int*)d_in[2];
    const float* out_scale    = (const float*)d_in[3];
    float*       out          = (float*)d_out;
    int*         DA           = (int*)d_ws;   // 17 * 32 * 4 B = 2176 B

    build_da_kernel<<<dim3(1), dim3(32), 0, stream>>>(x, DA);
    dl_dp_kernel<<<dim3(NBS * 16), dim3(64), 0, stream>>>(
        x, words, word_lengths, out_scale, DA, out);
}

// Round 2
// 74.015 us; speedup vs baseline: 2.6889x; 2.6889x over previous
//
#include <hip/hip_runtime.h>

#define ML 16
#define NW 1000
#define NBS 64

// charmask[c] (c=0..31): bit i (i=1..16) set iff any of the 64 sequences has
// char c at x-position (i-2) & 15  (row i of the DP uses x[:,:,i-2], Python
// negative-index wrap: i=1 -> pos 15, i>=2 -> pos i-2).
__global__ __launch_bounds__(64) void build_cm_kernel(const int* __restrict__ x,
                                                      unsigned* __restrict__ cm_g) {
    __shared__ unsigned cm[32];
    const int t = threadIdx.x;          // 64 threads, one per (b,s) sequence
    if (t < 32) cm[t] = 0u;
    __syncthreads();
    const int* xr = x + t * ML;
    #pragma unroll
    for (int p = 0; p < ML; ++p) {
        int c = xr[p];                  // 0..27
        int i = (p <= 14) ? (p + 2) : 1;
        atomicOr(&cm[c], 1u << i);
    }
    __syncthreads();
    if (t < 32) cm_g[t] = cm[t];
}

// One lane per (b,s,word). Entire DP in registers:
//  - prev[16]: previous DP row
//  - mk[t]   : maxdist - k_t  (k_t = DA[i][wc[t]]; k=0 -> mk=maxdist)
//  - tb[t]   : snap - k  where snap = DP(k, t+1) at last row k where wc[t]
//              appeared (k=0 -> tb=maxdist, folds the border case)
// Transposition term per cell (i,j), t=j-2:
//   l==0          -> trans = mk[t] + (i + j - 1)
//   l=j-1, k==i   -> trans = left   (previous cell in current row)
//   l=j-1, k<i    -> trans = tb[t] + i
__global__ __launch_bounds__(64) void dl_dp_kernel(
    const int* __restrict__ x,
    const int* __restrict__ words,
    const int* __restrict__ word_lengths,
    const float* __restrict__ out_scale,
    const unsigned* __restrict__ cm_g,
    float* __restrict__ out)
{
    const int lane = threadIdx.x;
    const int bs = blockIdx.x >> 4;          // 0..63
    const int chunk = blockIdx.x & 15;       // 0..15
    const int w_raw = chunk * 64 + lane;
    const bool active = (w_raw < NW);
    const int w = active ? w_raw : (NW - 1);
    const float s = out_scale[0];

    // wave-uniform x row: argmin (first min) = seq_wl
    const int* xr = x + bs * ML;
    int xc[ML];
    #pragma unroll
    for (int p = 0; p < ML; ++p) xc[p] = xr[p];
    int minv = xc[0], seq_wl = 0;
    #pragma unroll
    for (int p = 1; p < ML; ++p)
        if (xc[p] < minv) { minv = xc[p]; seq_wl = p; }

    // per-lane word chars (coalesced 16B loads) + row bitmasks
    int wc[ML];
    const int4* wp = (const int4*)(words + w * ML);
    int4 q0 = wp[0], q1 = wp[1], q2 = wp[2], q3 = wp[3];
    wc[0]=q0.x; wc[1]=q0.y; wc[2]=q0.z; wc[3]=q0.w;
    wc[4]=q1.x; wc[5]=q1.y; wc[6]=q1.z; wc[7]=q1.w;
    wc[8]=q2.x; wc[9]=q2.y; wc[10]=q2.z; wc[11]=q2.w;
    wc[12]=q3.x; wc[13]=q3.y; wc[14]=q3.z; wc[15]=q3.w;

    unsigned rm[ML];
    #pragma unroll
    for (int t = 0; t < ML; ++t) rm[t] = cm_g[wc[t]];

    const int wl = word_lengths[w];
    const float maxdist = (float)(seq_wl + wl) * s;

    float prev[ML], tb[15], mk[ML];
    #pragma unroll
    for (int j = 0; j < ML; ++j) prev[j] = maxdist;
    #pragma unroll
    for (int t = 0; t < 15; ++t) tb[t] = maxdist;
    #pragma unroll
    for (int t = 0; t < ML; ++t) mk[t] = maxdist;

    float res = 0.0f;
    const int sq1 = seq_wl + 1;       // wave-uniform capture column
    const int rowcap = wl + 1;        // per-lane capture row (17 -> never -> 0)

    int xi_next = xr[15];             // p for i=1
    #pragma unroll 1
    for (int i = 1; i <= ML; ++i) {
        const int xi = xi_next;
        if (i < ML) xi_next = xr[(i - 1) & 15];   // p for i+1
        const float fi = (float)i;
        const float md_i = maxdist - fi;

        bool b[ML];
        #pragma unroll
        for (int t = 0; t < ML; ++t) b[t] = ((rm[t] >> i) & 1u) != 0u;
        #pragma unroll
        for (int t = 0; t < 15; ++t) if (b[t]) mk[t] = md_i;  // DA[i] level
        const bool hit_row = (i == rowcap);

        // ---- j = 1: char wc[15]; l = 0; k from DA[i-1] (mk[15] not yet updated)
        const bool eq1 = (xi == wc[15]);
        const float cost1 = eq1 ? 0.0f : 1.0f;
        const float trans1 = mk[15] + fi;              // maxdist + (i - k15)
        float cell = fminf(fminf(prev[0] + 1.0f, maxdist + 1.0f),
                           fminf(maxdist + cost1, trans1));
        if (b[15]) mk[15] = md_i;                      // now DA[i] level
        bool pm = eq1;
        float left = cell;
        float cur[ML];
        cur[0] = cell;
        if (b[0]) tb[0] = cell - fi;                   // snap DP(i,1) for t=0
        if (hit_row && sq1 == 1) res = cell;

        #pragma unroll
        for (int j = 2; j <= ML; ++j) {
            const int t = j - 2;
            const bool eq = (xi == wc[t]);
            const float cost = eq ? 0.0f : 1.0f;
            const float trans_l0 = mk[t] + (float)(i + j - 1);
            const float trans_ln = b[t] ? left : (tb[t] + fi);
            const float trans = pm ? trans_ln : trans_l0;
            const float up = prev[j - 1];
            const float diag = prev[j - 2];
            const float cellv = fminf(fminf(up + 1.0f, left + 1.0f),
                                      fminf(diag + cost, trans));
            cur[j - 1] = cellv;
            if (j <= 15 && b[j - 1]) tb[j - 1] = cellv - fi;  // snap DP(i,j) for t=j-1
            if (hit_row && j == sq1) res = cellv;
            pm = eq;
            left = cellv;
        }
        #pragma unroll
        for (int j = 0; j < ML; ++j) prev[j] = cur[j];
    }

    if (active) out[bs * NW + w] = res;
}

extern "C" void kernel_launch(void* const* d_in, const int* in_sizes, int n_in,
                              void* d_out, int out_size, void* d_ws, size_t ws_size,
                              hipStream_t stream) {
    const int*   x            = (const int*)d_in[0];
    const int*   words        = (const int*)d_in[1];
    const int*   word_lengths = (const int*)d_in[2];
    const float* out_scale    = (const float*)d_in[3];
    float*       out          = (float*)d_out;
    unsigned*    cm           = (unsigned*)d_ws;   // 32 * 4 B

    build_cm_kernel<<<dim3(1), dim3(64), 0, stream>>>(x, cm);
    dl_dp_kernel<<<dim3(NBS * 16), dim3(64), 0, stream>>>(
        x, words, word_lengths, out_scale, cm, out);
}

// Round 3
// 71.244 us; speedup vs baseline: 2.7934x; 1.0389x over previous
//
#include <hip/hip_runtime.h>

#define ML 16
#define NW 1000
#define NBS 64

// Fused kernel: each block rebuilds the global char->row bitmask from x
// (4 KB, L2-resident) in LDS, then runs the register-resident DP.
//
// charmask cm[c]: bit i (i=1..16) set iff any of the 64 sequences has char c
// at x-position (i-2) & 15  (row i uses x[:,:,i-2]; Python negative-index
// wrap: i=1 -> pos 15).
//
// Per-lane DP state (one lane per (b,s,word)):
//  - prev[16]: previous DP row
//  - mk[t]   : maxdist - k_t  (k_t = DA[i][wc[t]]; k=0 -> mk=maxdist)
//  - tb[t]   : DP(k, t+1) - k at last row k where wc[t] appeared
//              (k=0 -> tb=maxdist, folds the border case)
// Transposition term per cell (i,j), t=j-2:
//   l==0          -> trans = mk[t] + (i + j - 1)
//   l=j-1, k==i   -> trans = left   (previous cell in current row)
//   l=j-1, k<i    -> trans = tb[t] + i
__global__ __launch_bounds__(256) void dl_fused_kernel(
    const int* __restrict__ x,
    const int* __restrict__ words,
    const int* __restrict__ word_lengths,
    const float* __restrict__ out_scale,
    float* __restrict__ out)
{
    __shared__ unsigned cm[32];
    const int tid = threadIdx.x;
    const int lane = tid & 63;
    const int wv = tid >> 6;                     // 0..3
    const int bs = blockIdx.x >> 2;              // 0..63
    const int chunk = (blockIdx.x & 3) * 4 + wv; // 0..15
    const int w_raw = chunk * 64 + lane;
    const bool active = (w_raw < NW);
    const int w = active ? w_raw : (NW - 1);
    const float s = out_scale[0];

    // ---- build charmask in LDS (lanes of wave 0..3 cooperate; 64 seqs) ----
    if (tid < 32) cm[tid] = 0u;
    __syncthreads();
    if (tid < 64) {
        const int* xq = x + tid * ML;
        #pragma unroll
        for (int p = 0; p < ML; ++p) {
            int c = xq[p];                       // 0..27
            int i = (p <= 14) ? (p + 2) : 1;
            atomicOr(&cm[c], 1u << i);
        }
    }
    __syncthreads();

    // ---- wave-uniform x row: argmin (first min) = seq_wl ----
    const int* xr = x + bs * ML;
    int xc[ML];
    #pragma unroll
    for (int p = 0; p < ML; ++p) xc[p] = xr[p];
    int minv = xc[0], seq_wl = 0;
    #pragma unroll
    for (int p = 1; p < ML; ++p)
        if (xc[p] < minv) { minv = xc[p]; seq_wl = p; }

    // ---- per-lane word chars (coalesced 16B loads) + row bitmasks ----
    int wc[ML];
    const int4* wp = (const int4*)(words + w * ML);
    int4 q0 = wp[0], q1 = wp[1], q2 = wp[2], q3 = wp[3];
    wc[0]=q0.x; wc[1]=q0.y; wc[2]=q0.z; wc[3]=q0.w;
    wc[4]=q1.x; wc[5]=q1.y; wc[6]=q1.z; wc[7]=q1.w;
    wc[8]=q2.x; wc[9]=q2.y; wc[10]=q2.z; wc[11]=q2.w;
    wc[12]=q3.x; wc[13]=q3.y; wc[14]=q3.z; wc[15]=q3.w;

    unsigned rm[ML];
    #pragma unroll
    for (int t = 0; t < ML; ++t) rm[t] = cm[wc[t]];

    const int wl = word_lengths[w];
    const float maxdist = (float)(seq_wl + wl) * s;

    float prev[ML], tb[15], mk[ML];
    #pragma unroll
    for (int j = 0; j < ML; ++j) prev[j] = maxdist;
    #pragma unroll
    for (int t = 0; t < 15; ++t) tb[t] = maxdist;
    #pragma unroll
    for (int t = 0; t < ML; ++t) mk[t] = maxdist;

    float res = 0.0f;
    const int sq1 = seq_wl + 1;       // wave-uniform capture column
    const int rowcap = wl + 1;        // per-lane capture row (17 -> never -> 0)

    int xi_next = xc[15];             // p for i=1
    #pragma unroll 1
    for (int i = 1; i <= ML; ++i) {
        const int xi = xi_next;
        if (i < ML) xi_next = xc[(i - 1) & 15];   // p for i+1
        const float fi = (float)i;
        const float md_i = maxdist - fi;

        bool b[ML];
        #pragma unroll
        for (int t = 0; t < ML; ++t) b[t] = ((rm[t] >> i) & 1u) != 0u;
        #pragma unroll
        for (int t = 0; t < 15; ++t) if (b[t]) mk[t] = md_i;  // DA[i] level
        const bool hit_row = (i == rowcap);

        // ---- j = 1: char wc[15]; l = 0; k from DA[i-1] (mk[15] not yet updated)
        const bool eq1 = (xi == wc[15]);
        const float cost1 = eq1 ? 0.0f : 1.0f;
        const float trans1 = mk[15] + fi;              // maxdist + (i - k15)
        float cell = fminf(fminf(prev[0] + 1.0f, maxdist + 1.0f),
                           fminf(maxdist + cost1, trans1));
        if (b[15]) mk[15] = md_i;                      // now DA[i] level
        bool pm = eq1;
        float left = cell;
        float cur[ML];
        cur[0] = cell;
        if (b[0]) tb[0] = cell - fi;                   // snap DP(i,1) for t=0
        if (hit_row && sq1 == 1) res = cell;

        #pragma unroll
        for (int j = 2; j <= ML; ++j) {
            const int t = j - 2;
            const bool eq = (xi == wc[t]);
            const float cost = eq ? 0.0f : 1.0f;
            const float trans_l0 = mk[t] + (float)(i + j - 1);
            const float trans_ln = b[t] ? left : (tb[t] + fi);
            const float trans = pm ? trans_ln : trans_l0;
            const float up = prev[j - 1];
            const float diag = prev[j - 2];
            const float cellv = fminf(fminf(up + 1.0f, left + 1.0f),
                                      fminf(diag + cost, trans));
            cur[j - 1] = cellv;
            if (j <= 15 && b[j - 1]) tb[j - 1] = cellv - fi;  // snap DP(i,j) for t=j-1
            if (hit_row && j == sq1) res = cellv;
            pm = eq;
            left = cellv;
        }
        #pragma unroll
        for (int j = 0; j < ML; ++j) prev[j] = cur[j];
    }

    if (active) out[bs * NW + w] = res;
}

extern "C" void kernel_launch(void* const* d_in, const int* in_sizes, int n_in,
                              void* d_out, int out_size, void* d_ws, size_t ws_size,
                              hipStream_t stream) {
    const int*   x            = (const int*)d_in[0];
    const int*   words        = (const int*)d_in[1];
    const int*   word_lengths = (const int*)d_in[2];
    const float* out_scale    = (const float*)d_in[3];
    float*       out          = (float*)d_out;

    dl_fused_kernel<<<dim3(NBS * 4), dim3(256), 0, stream>>>(
        x, words, word_lengths, out_scale, out);
}